// Round 15
// baseline (632.964 us; speedup 1.0000x reference)
//
#include <hip/hip_runtime.h>
#include <math.h>

// Problem constants (fixed by the reference)
#define NN   100000
#define FIN  1024
#define HIDN 16
#define CCH  64
#define EE   3200000
#define BNEPS 1e-5f
#define NB   ((NN + 255) / 256)   // 391 scan blocks
#define NPART 8                   // XCD count
#define PSZ  (NN / NPART)         // 12500 nodes per partition

typedef __attribute__((ext_vector_type(8))) short bf16x8;
typedef __attribute__((ext_vector_type(4))) float f32x4;

// ---------------------------------------------------------------------------
// k_hist: XCD-partitioned in-degree histogram; int4 edge reads (4x fewer
// VMEM issues on the 8x-redundant scan; kernel is issue/latency-bound)
// ---------------------------------------------------------------------------
__global__ __launch_bounds__(256) void k_hist(const int* __restrict__ ei,
                                              unsigned* __restrict__ deg) {
  int p = blockIdx.x & 7;
  int blk = blockIdx.x >> 3;
  int nblk = gridDim.x >> 3;
  int lo = p * PSZ, hi = lo + PSZ;
  for (int e4 = (blk * 256 + threadIdx.x) * 4; e4 < EE; e4 += nblk * 256 * 4) {
    int4 d4 = *(const int4*)(ei + EE + e4);
    if (d4.x >= lo && d4.x < hi) atomicAdd(&deg[d4.x], 1u);
    if (d4.y >= lo && d4.y < hi) atomicAdd(&deg[d4.y], 1u);
    if (d4.z >= lo && d4.z < hi) atomicAdd(&deg[d4.z], 1u);
    if (d4.w >= lo && d4.w < hi) atomicAdd(&deg[d4.w], 1u);
  }
}

// ---------------------------------------------------------------------------
// exclusive scan of deg -> rowptr (+ cur copy, + dis = rsqrt(deg+1))
// ---------------------------------------------------------------------------
__global__ __launch_bounds__(256) void k_scan_part(const unsigned* __restrict__ deg,
                                                   unsigned* __restrict__ exc,
                                                   unsigned* __restrict__ bsum) {
  __shared__ unsigned s[256];
  int t = threadIdx.x, i = blockIdx.x * 256 + t;
  unsigned v = (i < NN) ? deg[i] : 0u;
  s[t] = v;
  __syncthreads();
#pragma unroll
  for (int off = 1; off < 256; off <<= 1) {
    unsigned u = (t >= off) ? s[t - off] : 0u;
    __syncthreads();
    s[t] += u;
    __syncthreads();
  }
  if (i < NN) exc[i] = s[t] - v;
  if (t == 255) bsum[blockIdx.x] = s[255];
}

__global__ __launch_bounds__(512) void k_scan_boff(const unsigned* __restrict__ bsum,
                                                   unsigned* __restrict__ boff) {
  __shared__ unsigned s[512];
  int t = threadIdx.x;
  unsigned v = (t < NB) ? bsum[t] : 0u;
  s[t] = v;
  __syncthreads();
#pragma unroll
  for (int off = 1; off < 512; off <<= 1) {
    unsigned u = (t >= off) ? s[t - off] : 0u;
    __syncthreads();
    s[t] += u;
    __syncthreads();
  }
  if (t < NB) boff[t] = s[t] - v;
}

__global__ __launch_bounds__(256) void k_scan_final(const unsigned* __restrict__ exc,
                                                    const unsigned* __restrict__ boff,
                                                    const unsigned* __restrict__ deg,
                                                    int* __restrict__ rowptr,
                                                    int* __restrict__ cur,
                                                    float* __restrict__ dis) {
  int i = blockIdx.x * 256 + threadIdx.x;
  if (i < NN) {
    int r = (int)(boff[i >> 8] + exc[i]);
    rowptr[i] = r;
    cur[i] = r;
    dis[i] = rsqrtf((float)(deg[i] + 1u));
  } else if (i == NN) {
    rowptr[NN] = EE;
  }
}

// ---------------------------------------------------------------------------
// k_place: XCD-partitioned bucket placement; int4 dst reads, scalar src
// loads only on match (cur + perm slices stay L2-local per XCD)
// ---------------------------------------------------------------------------
__global__ __launch_bounds__(256) void k_place(const int* __restrict__ ei,
                                               int* __restrict__ cur,
                                               int* __restrict__ perm) {
  int p = blockIdx.x & 7;
  int blk = blockIdx.x >> 3;
  int nblk = gridDim.x >> 3;
  int lo = p * PSZ, hi = lo + PSZ;
  for (int e4 = (blk * 256 + threadIdx.x) * 4; e4 < EE; e4 += nblk * 256 * 4) {
    int4 d4 = *(const int4*)(ei + EE + e4);
    if (d4.x >= lo && d4.x < hi) perm[atomicAdd(&cur[d4.x], 1)] = ei[e4 + 0];
    if (d4.y >= lo && d4.y < hi) perm[atomicAdd(&cur[d4.y], 1)] = ei[e4 + 1];
    if (d4.z >= lo && d4.z < hi) perm[atomicAdd(&cur[d4.z], 1)] = ei[e4 + 2];
    if (d4.w >= lo && d4.w < hi) perm[atomicAdd(&cur[d4.w], 1)] = ei[e4 + 3];
  }
}

// ---------------------------------------------------------------------------
// pk_bf16: RNE-pack two f32 into one dword of 2 bf16 (lo | hi<<16)
// ---------------------------------------------------------------------------
__device__ __forceinline__ unsigned pk_bf16(float lo, float hi) {
  unsigned ul = __float_as_uint(lo);
  unsigned uh = __float_as_uint(hi);
  ul = (ul + 0x7fffu + ((ul >> 16) & 1u)) >> 16;
  uh = (uh + 0x7fffu + ((uh >> 16) & 1u)) & 0xffff0000u;
  return ul | uh;
}

// ---------------------------------------------------------------------------
// k_w1bf16: one-time w1 -> bf16 col-major [16][1024] in global (32 KB;
// L2-resident on every XCD for the gemm's B-fragment loads)
// ---------------------------------------------------------------------------
__global__ __launch_bounds__(256) void k_w1bf16(const float* __restrict__ w1,
                                                unsigned short* __restrict__ w1b) {
  for (int idx = blockIdx.x * 256 + threadIdx.x; idx < 1024 * 16;
       idx += gridDim.x * 256) {
    int k = idx >> 4, j = idx & 15;
    unsigned u = __float_as_uint(w1[idx]);
    u = (u + 0x7fffu + ((u >> 16) & 1u)) >> 16;   // RNE to bf16
    w1b[j * 1024 + k] = (unsigned short)u;
  }
}

// ---------------------------------------------------------------------------
// k_gemm1 (ROUND-15, LDS-FREE MFMA): xw1s[N,16] = (x@w1)*dis_i.
// r14 lesson: 391-block grid (1.5 blocks/CU) + per-block 33KB staging was
// the limit, not the math. Now B-frags load from the 32KB global bf16 table
// (L2-hot on all XCDs) -> no LDS, no staging, 64 rows/block, grid 1563
// (6 blocks/CU), VGPR ~60 -> ~24 waves/CU in flight -> x stream HBM-bound.
// Fragments (m89, validated by r14 absmax): A lane l = row l&15,
// k=(l>>4)*8+j; B lane l = col l&15; D row=(l>>4)*4+r, col=l&15.
// ---------------------------------------------------------------------------
__global__ __launch_bounds__(256) void k_gemm1(const float* __restrict__ x,
                                               const unsigned short* __restrict__ w1b,
                                               const float* __restrict__ dis,
                                               float* __restrict__ xw1s) {
  const int lane = threadIdx.x & 63;
  const int wave = threadIdx.x >> 6;
  const int m = lane & 15;        // A row / B col / D col
  const int kg = lane >> 4;       // k-group 0..3

  int row0 = blockIdx.x * 64 + wave * 16;
  int rowA = min(row0 + m, NN - 1);
  const float* xrow = x + (size_t)rowA * FIN + kg * 8;
  const unsigned short* bbase = w1b + m * 1024 + kg * 8;

  f32x4 acc = {0.0f, 0.0f, 0.0f, 0.0f};

#pragma unroll
  for (int ks = 0; ks < 32; ks += 4) {
    f32x4 A0[4], A1[4];
#pragma unroll
    for (int u = 0; u < 4; ++u) {
      const f32x4* pa = (const f32x4*)(xrow + (ks + u) * 32);
      A0[u] = __builtin_nontemporal_load(pa);
      A1[u] = __builtin_nontemporal_load(pa + 1);
    }
#pragma unroll
    for (int u = 0; u < 4; ++u) {
      union { unsigned w[4]; bf16x8 s; } af;
      af.w[0] = pk_bf16(A0[u].x, A0[u].y);
      af.w[1] = pk_bf16(A0[u].z, A0[u].w);
      af.w[2] = pk_bf16(A1[u].x, A1[u].y);
      af.w[3] = pk_bf16(A1[u].z, A1[u].w);
      bf16x8 bfrag = *(const bf16x8*)(bbase + (ks + u) * 32);
      acc = __builtin_amdgcn_mfma_f32_16x16x32_bf16(af.s, bfrag, acc, 0, 0, 0);
    }
  }

  // D: lane l holds D[kg*4+r][m]
#pragma unroll
  for (int r = 0; r < 4; ++r) {
    int grow = row0 + kg * 4 + r;
    if (grow < NN) xw1s[grow * HIDN + m] = acc[r] * dis[grow];
  }
}

// ---------------------------------------------------------------------------
// k_agg1: CSR gather-reduce layer 1, ONE WAVE PER NODE, unroll-2.
//   out = relu(dis_i*(sum_e sfs[perm[e]] + sfs[i]) + b1[j]) * dis_i
// ---------------------------------------------------------------------------
__global__ __launch_bounds__(256) void k_agg1(const int* __restrict__ rowptr,
                                              const int* __restrict__ perm,
                                              const float* __restrict__ dis,
                                              const float* __restrict__ sfs,
                                              const float* __restrict__ b1,
                                              float* __restrict__ out) {
  int g = blockIdx.x * 4 + (threadIdx.x >> 6);     // node (wave id)
  if (g >= NN) return;
  int lane = threadIdx.x & 63;
  int eo = lane >> 4;                              // 0..3
  int j = lane & 15;                               // channel
  int beg = rowptr[g], end = rowptr[g + 1];
  float acc0 = 0.0f, acc1 = 0.0f;
  int e = beg + eo;
  for (; e + 4 < end; e += 8) {
    int s0 = perm[e];
    int s1 = perm[e + 4];
    acc0 += sfs[(size_t)s0 * HIDN + j];
    acc1 += sfs[(size_t)s1 * HIDN + j];
  }
  if (e < end) acc0 += sfs[(size_t)perm[e] * HIDN + j];
  float acc = acc0 + acc1;
  acc += __shfl_xor(acc, 16, 64);
  acc += __shfl_xor(acc, 32, 64);
  if (eo == 0) {
    float di = dis[g];
    float v = di * (acc + sfs[(size_t)g * HIDN + j]);
    out[(size_t)g * HIDN + j] = fmaxf(v + b1[j], 0.0f) * di;
  }
}

// ---------------------------------------------------------------------------
// k_aggfuse: layer-2 aggregation + full tail, ONE WAVE PER NODE (100K
// independent waves; tail VALU chain hides in the gather's latency shadow).
// BN stats in separate streaming pass.
// ---------------------------------------------------------------------------
__global__ __launch_bounds__(256) void k_aggfuse(const int* __restrict__ rowptr,
                                                 const int* __restrict__ perm,
                                                 const float* __restrict__ dis,
                                                 const float* __restrict__ sfs,
                                                 const float* __restrict__ w2,
                                                 const float* __restrict__ b2,
                                                 const float* __restrict__ mlpw,
                                                 const float* __restrict__ mlpb,
                                                 const float* __restrict__ wraw,
                                                 float* __restrict__ out) {
  __shared__ __align__(16) float2 w2p[8 * CCH];     // (w2[2k][j], w2[2k+1][j])
  __shared__ __align__(16) float2 mlpp[32 * CCH];   // (mlp[2c][j], mlp[2c+1][j])
  __shared__ __align__(16) float avbuf[4][HIDN];
  __shared__ __align__(16) float gbuf[4][CCH];
  for (int idx = threadIdx.x; idx < 8 * CCH; idx += 256) {
    int k2 = idx >> 6, j = idx & 63;
    w2p[idx] = make_float2(w2[(2 * k2) * CCH + j], w2[(2 * k2 + 1) * CCH + j]);
  }
  for (int idx = threadIdx.x; idx < 32 * CCH; idx += 256) {
    int c2 = idx >> 6, j = idx & 63;
    mlpp[idx] = make_float2(mlpw[(2 * c2) * CCH + j], mlpw[(2 * c2 + 1) * CCH + j]);
  }
  __syncthreads();

  const int g = blockIdx.x * 4 + (threadIdx.x >> 6);   // node (wave id)
  if (g >= NN) return;
  const int lane = threadIdx.x & 63;
  const int wave = threadIdx.x >> 6;
  const int eo = lane >> 4;
  const int jc = lane & 15;      // agg channel
  const int j = lane;            // tail channel 0..63

  // ---- layer-2 aggregation (features pre-scaled by dis[src]) ----
  int beg = rowptr[g], end = rowptr[g + 1];
  float acc0 = 0.0f, acc1 = 0.0f;
  int e = beg + eo;
  for (; e + 4 < end; e += 8) {
    int s0 = perm[e];
    int s1 = perm[e + 4];
    acc0 += sfs[(size_t)s0 * HIDN + jc];
    acc1 += sfs[(size_t)s1 * HIDN + jc];
  }
  if (e < end) acc0 += sfs[(size_t)perm[e] * HIDN + jc];
  float acc = acc0 + acc1;
  acc += __shfl_xor(acc, 16, 64);
  acc += __shfl_xor(acc, 32, 64);
  float di = dis[g];
  float av = di * (acc + sfs[(size_t)g * HIDN + jc]);  // valid in ALL lanes
  if (lane < HIDN) avbuf[wave][lane] = av;

  // ---- h2 = av @ w2 + b2 ----
  float2 h2p = make_float2(0.0f, 0.0f);
#pragma unroll
  for (int k2 = 0; k2 < 8; ++k2) {
    float2 a = *(const float2*)&avbuf[wave][2 * k2];   // broadcast read
    float2 wv = w2p[k2 * CCH + j];
    h2p.x = fmaf(a.x, wv.x, h2p.x);
    h2p.y = fmaf(a.y, wv.y, h2p.y);
  }
  float h2 = h2p.x + h2p.y + b2[j];

  // ---- log_softmax ----
  float mx = h2;
#pragma unroll
  for (int o = 32; o >= 1; o >>= 1) mx = fmaxf(mx, __shfl_xor(mx, o, 64));
  float ex = __expf(h2 - mx);
  float se = ex;
#pragma unroll
  for (int o = 32; o >= 1; o >>= 1) se += __shfl_xor(se, o, 64);
  float lsm = h2 - mx - __logf(se);

  // ---- channel weight + MLP ----
  float gg = __expf(wraw[g]) * lsm;
  gbuf[wave][j] = gg;

  float2 mp = make_float2(0.0f, 0.0f);
#pragma unroll
  for (int c2 = 0; c2 < 32; ++c2) {
    float2 gv = *(const float2*)&gbuf[wave][2 * c2];   // broadcast read
    float2 wv = mlpp[c2 * CCH + j];
    mp.x = fmaf(gv.x, wv.x, mp.x);
    mp.y = fmaf(gv.y, wv.y, mp.y);
  }
  out[(size_t)g * CCH + j] = mp.x + mp.y + mlpb[j];
}

// ---------------------------------------------------------------------------
// k_bnstats: streaming f64 sum/sumsq over out (coalesced; 256 blocks ->
// only 256 atomics per channel address)
// ---------------------------------------------------------------------------
__global__ __launch_bounds__(256) void k_bnstats(const float* __restrict__ out,
                                                 double* __restrict__ gsum,
                                                 double* __restrict__ gsq) {
  __shared__ double reds[256];
  __shared__ double redq[256];
  const int lane = threadIdx.x & 63;
  const int wave = threadIdx.x >> 6;
  double s = 0.0, q = 0.0;
  for (int i = blockIdx.x * 4 + wave; i < NN; i += gridDim.x * 4) {
    float m = out[(size_t)i * CCH + lane];
    s += (double)m;
    q = fma((double)m, (double)m, q);
  }
  reds[threadIdx.x] = s;
  redq[threadIdx.x] = q;
  __syncthreads();
  if (threadIdx.x < 64) {
    double ss = reds[threadIdx.x] + reds[threadIdx.x + 64] +
                reds[threadIdx.x + 128] + reds[threadIdx.x + 192];
    double qq = redq[threadIdx.x] + redq[threadIdx.x + 64] +
                redq[threadIdx.x + 128] + redq[threadIdx.x + 192];
    atomicAdd(&gsum[threadIdx.x], ss);
    atomicAdd(&gsq[threadIdx.x], qq);
  }
}

// ---------------------------------------------------------------------------
// k_out: BN finalize (folded, per-thread from gsum/gsq) + apply + final
// log_softmax, in-place on d_out (wave per row)
// ---------------------------------------------------------------------------
__global__ __launch_bounds__(256) void k_out(float* __restrict__ out,
                                             const double* __restrict__ gsum,
                                             const double* __restrict__ gsq,
                                             const float* __restrict__ gamma,
                                             const float* __restrict__ beta) {
  const int lane = threadIdx.x & 63;
  const int wave = threadIdx.x >> 6;
  const int j = lane;
  const double inv_n = 1.0 / (double)NN;
  double md = gsum[j] * inv_n;
  double var = gsq[j] * inv_n - md * md;
  const float sc = (float)(rsqrt(var + (double)BNEPS)) * gamma[j];
  const float mean = (float)md;
  const float bt = beta[j];
  const int gw = blockIdx.x * 4 + wave;
  const int nw = gridDim.x * 4;
  for (int i = gw; i < NN; i += nw) {
    float m = out[(size_t)i * CCH + j];
    float y = fmaf(m - mean, sc, bt);
    float mx = y;
#pragma unroll
    for (int o = 32; o >= 1; o >>= 1) mx = fmaxf(mx, __shfl_xor(mx, o, 64));
    float ex = __expf(y - mx);
    float se = ex;
#pragma unroll
    for (int o = 32; o >= 1; o >>= 1) se += __shfl_xor(se, o, 64);
    out[(size_t)i * CCH + j] = y - mx - __logf(se);
  }
}

// ---------------------------------------------------------------------------
extern "C" void kernel_launch(void* const* d_in, const int* in_sizes, int n_in,
                              void* d_out, int out_size, void* d_ws, size_t ws_size,
                              hipStream_t stream) {
  const float* x     = (const float*)d_in[0];
  const int*   ei    = (const int*)d_in[1];
  const float* w1    = (const float*)d_in[2];
  const float* b1    = (const float*)d_in[3];
  const float* w2    = (const float*)d_in[4];
  const float* b2    = (const float*)d_in[5];
  const float* mlpw  = (const float*)d_in[6];
  const float* mlpb  = (const float*)d_in[7];
  const float* gamma = (const float*)d_in[8];
  const float* beta  = (const float*)d_in[9];
  const float* wraw  = (const float*)d_in[10];
  float* out = (float*)d_out;

  // workspace carve (256B aligned slots)
  char* w = (char*)d_ws;
  size_t off = 0;
  auto take = [&](size_t bytes) -> void* {
    void* p = w + off;
    off = (off + bytes + 255) & ~(size_t)255;
    return p;
  };
  unsigned*       deg    = (unsigned*)take((size_t)NN * 4);
  float*          dis    = (float*)take((size_t)NN * 4);
  unsigned*       exc    = (unsigned*)take((size_t)NN * 4);
  unsigned*       bsum   = (unsigned*)take((size_t)NB * 4);
  unsigned*       boff   = (unsigned*)take((size_t)NB * 4);
  int*            rowptr = (int*)take((size_t)(NN + 1) * 4);
  int*            cur    = (int*)take((size_t)NN * 4);
  int*            perm   = (int*)take((size_t)EE * 4);
  float*          xw1s   = (float*)take((size_t)NN * HIDN * 4);
  float*          rh1s   = (float*)take((size_t)NN * HIDN * 4);
  unsigned short* w1b    = (unsigned short*)take((size_t)16 * 1024 * 2);
  double*         gsum   = (double*)take(CCH * 8);
  double*         gsq    = (double*)take(CCH * 8);
  (void)ws_size; (void)n_in; (void)in_sizes; (void)out_size;

  hipMemsetAsync(deg, 0, (size_t)NN * 4, stream);
  hipMemsetAsync(gsum, 0, CCH * 8, stream);
  hipMemsetAsync(gsq, 0, CCH * 8, stream);

  // CSR build: XCD-partitioned histogram -> scan -> XCD-partitioned place
  k_hist<<<2048, 256, 0, stream>>>(ei, deg);
  k_scan_part<<<NB, 256, 0, stream>>>(deg, exc, bsum);
  k_scan_boff<<<1, 512, 0, stream>>>(bsum, boff);
  k_scan_final<<<(NN + 256) / 256 + 1, 256, 0, stream>>>(exc, boff, deg, rowptr, cur, dis);
  k_place<<<2048, 256, 0, stream>>>(ei, cur, perm);

  // dense transform (LDS-free MFMA) + layer-1 agg + fused layer-2 tail
  k_w1bf16<<<16, 256, 0, stream>>>(w1, w1b);
  k_gemm1<<<(NN + 63) / 64, 256, 0, stream>>>(x, w1b, dis, xw1s);
  k_agg1<<<(NN + 3) / 4, 256, 0, stream>>>(rowptr, perm, dis, xw1s, b1, rh1s);
  k_aggfuse<<<(NN + 3) / 4, 256, 0, stream>>>(rowptr, perm, dis, rh1s, w2, b2,
                                              mlpw, mlpb, wraw, out);

  // BN stats + apply (k_stats folded into k_out)
  k_bnstats<<<256, 256, 0, stream>>>(out, gsum, gsq);
  k_out<<<1024, 256, 0, stream>>>(out, gsum, gsq, gamma, beta);
}